// Round 2
// baseline (594.823 us; speedup 1.0000x reference)
//
#include <hip/hip_runtime.h>
#include <math.h>

#define NN 65536
#define HH 128
#define NHEADS 8
#define DHH 16
#define NE 1048576
#define HID 256
#define LNEPS 1e-5f

static __device__ __forceinline__ float gelu_tanh(float x) {
    const float c = 0.7978845608028654f;
    return 0.5f * x * (1.f + tanhf(c * (x + 0.044715f * x * x * x)));
}

// ---------------- CSR build ----------------
__global__ __launch_bounds__(256) void k_count(const int* __restrict__ er, int* __restrict__ cnt) {
    int e = blockIdx.x * 256 + threadIdx.x;
    atomicAdd(&cnt[er[e]], 1);
}

__global__ __launch_bounds__(1024) void k_scan(const int* __restrict__ cnt,
                                               int* __restrict__ offs, int* __restrict__ cursor) {
    __shared__ int part[1024];
    const int t = threadIdx.x;
    const int base = t * 64;
    int sum = 0;
    for (int i = 0; i < 64; i++) sum += cnt[base + i];
    part[t] = sum;
    __syncthreads();
    for (int d = 1; d < 1024; d <<= 1) {
        int vv = (t >= d) ? part[t - d] : 0;
        __syncthreads();
        part[t] += vv;
        __syncthreads();
    }
    int run = part[t] - sum;  // exclusive prefix of this thread's chunk
    for (int i = 0; i < 64; i++) {
        offs[base + i] = run;
        cursor[base + i] = run;
        run += cnt[base + i];
    }
    if (t == 1023) offs[NN] = run;
}

__global__ __launch_bounds__(256) void k_scatter(const int* __restrict__ er, const int* __restrict__ ec,
                                                 int* __restrict__ cursor, int* __restrict__ csr_col) {
    int e = blockIdx.x * 256 + threadIdx.x;
    int r = er[e];
    int p = atomicAdd(&cursor[r], 1);
    csr_col[p] = ec[e];
}

// ---------------- GEMM inner helper ----------------
// acc[i][j] += sum_k aT[k][r0+i] * W[k*WCOLS + c0 + j]
template <int KDIM, int WCOLS>
__device__ __forceinline__ void gemm_acc(const float (*aT)[64], const float* __restrict__ W,
                                         int r0, int c0, float acc[8][4]) {
#pragma unroll 4
    for (int kk = 0; kk < KDIM; kk++) {
        const float4 w4 = *reinterpret_cast<const float4*>(W + (size_t)kk * WCOLS + c0);
        const float4 a0 = *reinterpret_cast<const float4*>(&aT[kk][r0]);
        const float4 a1 = *reinterpret_cast<const float4*>(&aT[kk][r0 + 4]);
        const float av[8] = {a0.x, a0.y, a0.z, a0.w, a1.x, a1.y, a1.z, a1.w};
#pragma unroll
        for (int i = 0; i < 8; i++) {
            acc[i][0] += av[i] * w4.x;
            acc[i][1] += av[i] * w4.y;
            acc[i][2] += av[i] * w4.z;
            acc[i][3] += av[i] * w4.w;
        }
    }
}

// ---------------- K1: LN1 + QKV ----------------
__global__ __launch_bounds__(256) void k_ln_qkv(
    const float* __restrict__ x, const float* __restrict__ g, const float* __restrict__ bl,
    const float* __restrict__ wq, const float* __restrict__ bq,
    const float* __restrict__ wk, const float* __restrict__ bk,
    const float* __restrict__ wv, const float* __restrict__ bv,
    float* __restrict__ qo, float* __restrict__ ko, float* __restrict__ vo) {
    __shared__ float aT[HH][64];
    const int t = threadIdx.x;
    const int rowbase = blockIdx.x * 64;
    {
        const int r = t >> 2, qd = t & 3;
        const float* xr = x + (size_t)(rowbase + r) * HH + qd * 32;
        float4 xv[8];
        float s = 0.f, ss = 0.f;
#pragma unroll
        for (int i = 0; i < 8; i++) {
            xv[i] = reinterpret_cast<const float4*>(xr)[i];
            s += xv[i].x + xv[i].y + xv[i].z + xv[i].w;
            ss += xv[i].x * xv[i].x + xv[i].y * xv[i].y + xv[i].z * xv[i].z + xv[i].w * xv[i].w;
        }
        s += __shfl_xor(s, 1); s += __shfl_xor(s, 2);
        ss += __shfl_xor(ss, 1); ss += __shfl_xor(ss, 2);
        const float mu = s * (1.f / HH);
        const float rs = rsqrtf(ss * (1.f / HH) - mu * mu + LNEPS);
#pragma unroll
        for (int i = 0; i < 8; i++) {
            const int d = qd * 32 + i * 4;
            aT[d + 0][r] = (xv[i].x - mu) * rs * g[d + 0] + bl[d + 0];
            aT[d + 1][r] = (xv[i].y - mu) * rs * g[d + 1] + bl[d + 1];
            aT[d + 2][r] = (xv[i].z - mu) * rs * g[d + 2] + bl[d + 2];
            aT[d + 3][r] = (xv[i].w - mu) * rs * g[d + 3] + bl[d + 3];
        }
    }
    __syncthreads();
    const int r0 = (t >> 5) * 8;
    const int c0 = (t & 31) * 4;

    const float* Wm;
    const float* Bm;
    float* Om;
#pragma unroll 1
    for (int m = 0; m < 3; m++) {
        Wm = (m == 0) ? wq : (m == 1) ? wk : wv;
        Bm = (m == 0) ? bq : (m == 1) ? bk : bv;
        Om = (m == 0) ? qo : (m == 1) ? ko : vo;
        float acc[8][4] = {};
        gemm_acc<HH, HH>(aT, Wm, r0, c0, acc);
        const float4 bb = *reinterpret_cast<const float4*>(Bm + c0);
#pragma unroll
        for (int i = 0; i < 8; i++) {
            float4 o = make_float4(acc[i][0] + bb.x, acc[i][1] + bb.y, acc[i][2] + bb.z, acc[i][3] + bb.w);
            *reinterpret_cast<float4*>(Om + (size_t)(rowbase + r0 + i) * HH + c0) = o;
        }
    }
}

// ---------------- K3: fused SDDMM + softmax + SpMM over CSR ----------------
// one wave per row; lane = es*8 + h (es = edge slot 0..7, h = head 0..7)
__global__ __launch_bounds__(256) void k_attn(
    const float* __restrict__ q, const float* __restrict__ k, const float* __restrict__ v,
    const int* __restrict__ offs, const int* __restrict__ csr_col, float* __restrict__ agg) {
    const int wave = threadIdx.x >> 6;
    const int lane = threadIdx.x & 63;
    const int row = blockIdx.x * 4 + wave;
    const int h = lane & 7, es = lane >> 3;
    const int c0 = offs[row], c1 = offs[row + 1];
    const int cnt = c1 - c0;

    float4 qv[4];
    {
        const float4* qp = reinterpret_cast<const float4*>(q + (size_t)row * HH + h * DHH);
#pragma unroll
        for (int i = 0; i < 4; i++) qv[i] = qp[i];
    }
    float m = -INFINITY, den = 0.f;
    float acc[16] = {};

    for (int base = 0; base < cnt; base += 8) {
        const int ei = base + es;
        const bool act = ei < cnt;
        int col = 0;
        if (act) col = csr_col[c0 + ei];
        float sc = -INFINITY;
        if (act) {
            const float4* kp = reinterpret_cast<const float4*>(k + (size_t)col * HH + h * DHH);
            float dot = 0.f;
#pragma unroll
            for (int i = 0; i < 4; i++) {
                float4 kv = kp[i];
                dot += qv[i].x * kv.x + qv[i].y * kv.y + qv[i].z * kv.z + qv[i].w * kv.w;
            }
            sc = dot * 0.25f;  // 1/sqrt(16)
        }
        // chunk max per head across edge slots
        float cm = sc;
        cm = fmaxf(cm, __shfl_xor(cm, 8));
        cm = fmaxf(cm, __shfl_xor(cm, 16));
        cm = fmaxf(cm, __shfl_xor(cm, 32));
        const float nm = fmaxf(m, cm);
        const float scale = expf(m - nm);  // m=-inf first chunk -> 0
        const float p = act ? expf(sc - nm) : 0.f;
        den = den * scale + p;
#pragma unroll
        for (int i = 0; i < 16; i++) acc[i] *= scale;
        if (act) {
            const float4* vp = reinterpret_cast<const float4*>(v + (size_t)col * HH + h * DHH);
#pragma unroll
            for (int i = 0; i < 4; i++) {
                float4 vv = vp[i];
                acc[i * 4 + 0] += p * vv.x;
                acc[i * 4 + 1] += p * vv.y;
                acc[i * 4 + 2] += p * vv.z;
                acc[i * 4 + 3] += p * vv.w;
            }
        }
        m = nm;
    }
    // reduce over edge slots (lane bits 3..5)
#pragma unroll
    for (int d = 8; d < 64; d <<= 1) {
        den += __shfl_xor(den, d);
#pragma unroll
        for (int i = 0; i < 16; i++) acc[i] += __shfl_xor(acc[i], d);
    }
    const float inv = 1.f / (den + 1e-9f);
    if (es == 0) {
        float* ar = agg + (size_t)row * HH + h * DHH;
#pragma unroll
        for (int i = 0; i < 4; i++) {
            float4 o = make_float4(acc[i * 4 + 0] * inv, acc[i * 4 + 1] * inv,
                                   acc[i * 4 + 2] * inv, acc[i * 4 + 3] * inv);
            reinterpret_cast<float4*>(ar)[i] = o;
        }
    }
}

// ---------------- K4: h = x + agg@wo + bo ----------------
__global__ __launch_bounds__(256) void k_wo_res(
    const float* __restrict__ agg, const float* __restrict__ wo, const float* __restrict__ bo,
    const float* __restrict__ x, float* __restrict__ h) {
    __shared__ float aT[HH][64];
    const int t = threadIdx.x;
    const int rowbase = blockIdx.x * 64;
    {
        const int r = t >> 2, qd = t & 3;
        const float* ar = agg + (size_t)(rowbase + r) * HH + qd * 32;
#pragma unroll
        for (int i = 0; i < 8; i++) {
            float4 a4 = reinterpret_cast<const float4*>(ar)[i];
            const int d = qd * 32 + i * 4;
            aT[d + 0][r] = a4.x; aT[d + 1][r] = a4.y; aT[d + 2][r] = a4.z; aT[d + 3][r] = a4.w;
        }
    }
    __syncthreads();
    const int r0 = (t >> 5) * 8, c0 = (t & 31) * 4;
    float acc[8][4] = {};
    gemm_acc<HH, HH>(aT, wo, r0, c0, acc);
    const float4 bb = *reinterpret_cast<const float4*>(bo + c0);
#pragma unroll
    for (int i = 0; i < 8; i++) {
        const size_t idx = (size_t)(rowbase + r0 + i) * HH + c0;
        const float4 xr = *reinterpret_cast<const float4*>(x + idx);
        float4 o = make_float4(acc[i][0] + bb.x + xr.x, acc[i][1] + bb.y + xr.y,
                               acc[i][2] + bb.z + xr.z, acc[i][3] + bb.w + xr.w);
        *reinterpret_cast<float4*>(h + idx) = o;
    }
}

// ---------------- K6: t = gelu(LN2(h)@w1 + b1) ----------------
__global__ __launch_bounds__(256) void k_ln2_mlp1(
    const float* __restrict__ h, const float* __restrict__ g2, const float* __restrict__ bl2,
    const float* __restrict__ w1, const float* __restrict__ b1, float* __restrict__ tbuf) {
    __shared__ float aT[HH][64];
    const int t = threadIdx.x;
    const int rowbase = blockIdx.x * 64;
    {
        const int r = t >> 2, qd = t & 3;
        const float* xr = h + (size_t)(rowbase + r) * HH + qd * 32;
        float4 xv[8];
        float s = 0.f, ss = 0.f;
#pragma unroll
        for (int i = 0; i < 8; i++) {
            xv[i] = reinterpret_cast<const float4*>(xr)[i];
            s += xv[i].x + xv[i].y + xv[i].z + xv[i].w;
            ss += xv[i].x * xv[i].x + xv[i].y * xv[i].y + xv[i].z * xv[i].z + xv[i].w * xv[i].w;
        }
        s += __shfl_xor(s, 1); s += __shfl_xor(s, 2);
        ss += __shfl_xor(ss, 1); ss += __shfl_xor(ss, 2);
        const float mu = s * (1.f / HH);
        const float rs = rsqrtf(ss * (1.f / HH) - mu * mu + LNEPS);
#pragma unroll
        for (int i = 0; i < 8; i++) {
            const int d = qd * 32 + i * 4;
            aT[d + 0][r] = (xv[i].x - mu) * rs * g2[d + 0] + bl2[d + 0];
            aT[d + 1][r] = (xv[i].y - mu) * rs * g2[d + 1] + bl2[d + 1];
            aT[d + 2][r] = (xv[i].z - mu) * rs * g2[d + 2] + bl2[d + 2];
            aT[d + 3][r] = (xv[i].w - mu) * rs * g2[d + 3] + bl2[d + 3];
        }
    }
    __syncthreads();
    const int r0 = (t >> 5) * 8;
    const int c0 = blockIdx.y * 128 + (t & 31) * 4;
    float acc[8][4] = {};
    gemm_acc<HH, HID>(aT, w1, r0, c0, acc);
    const float4 bb = *reinterpret_cast<const float4*>(b1 + c0);
#pragma unroll
    for (int i = 0; i < 8; i++) {
        float4 o = make_float4(gelu_tanh(acc[i][0] + bb.x), gelu_tanh(acc[i][1] + bb.y),
                               gelu_tanh(acc[i][2] + bb.z), gelu_tanh(acc[i][3] + bb.w));
        *reinterpret_cast<float4*>(tbuf + (size_t)(rowbase + r0 + i) * HID + c0) = o;
    }
}

// ---------------- K7: out = h + t@w2 + b2 (in-place on d_out) ----------------
__global__ __launch_bounds__(256) void k_mlp2_res(
    const float* __restrict__ tbuf, const float* __restrict__ w2, const float* __restrict__ b2,
    float* __restrict__ out) {
    __shared__ float aT[HID][64];
    const int t = threadIdx.x;
    const int rowbase = blockIdx.x * 64;
    {
        const int r = t >> 2, qd = t & 3;
        const float* tr = tbuf + (size_t)(rowbase + r) * HID + qd * 64;
#pragma unroll
        for (int i = 0; i < 16; i++) {
            float4 a4 = reinterpret_cast<const float4*>(tr)[i];
            const int d = qd * 64 + i * 4;
            aT[d + 0][r] = a4.x; aT[d + 1][r] = a4.y; aT[d + 2][r] = a4.z; aT[d + 3][r] = a4.w;
        }
    }
    __syncthreads();
    const int r0 = (t >> 5) * 8, c0 = (t & 31) * 4;
    float acc[8][4] = {};
    gemm_acc<HID, HH>(aT, w2, r0, c0, acc);
    const float4 bb = *reinterpret_cast<const float4*>(b2 + c0);
#pragma unroll
    for (int i = 0; i < 8; i++) {
        const size_t idx = (size_t)(rowbase + r0 + i) * HH + c0;
        const float4 hv = *reinterpret_cast<const float4*>(out + idx);
        float4 o = make_float4(acc[i][0] + bb.x + hv.x, acc[i][1] + bb.y + hv.y,
                               acc[i][2] + bb.z + hv.z, acc[i][3] + bb.w + hv.w);
        *reinterpret_cast<float4*>(out + idx) = o;
    }
}

extern "C" void kernel_launch(void* const* d_in, const int* in_sizes, int n_in,
                              void* d_out, int out_size, void* d_ws, size_t ws_size,
                              hipStream_t stream) {
    const float* x = (const float*)d_in[0];
    const int* erow = (const int*)d_in[1];
    const int* ecol = (const int*)d_in[2];
    const float* ln1g = (const float*)d_in[3];
    const float* ln1b = (const float*)d_in[4];
    const float* wq = (const float*)d_in[5];
    const float* bq = (const float*)d_in[6];
    const float* wk = (const float*)d_in[7];
    const float* bk = (const float*)d_in[8];
    const float* wv = (const float*)d_in[9];
    const float* bv = (const float*)d_in[10];
    const float* wo = (const float*)d_in[11];
    const float* bo = (const float*)d_in[12];
    const float* ln2g = (const float*)d_in[13];
    const float* ln2b = (const float*)d_in[14];
    const float* w1 = (const float*)d_in[15];
    const float* b1 = (const float*)d_in[16];
    const float* w2 = (const float*)d_in[17];
    const float* b2 = (const float*)d_in[18];
    float* out = (float*)d_out;

    float* qb = (float*)d_ws;
    float* kb = qb + (size_t)NN * HH;
    float* vb = kb + (size_t)NN * HH;
    float* aggb = vb + (size_t)NN * HH;
    float* tbuf = qb;  // alias: q/k dead by the time MLP runs
    int* cnt = (int*)(aggb + (size_t)NN * HH);
    int* offs = cnt + NN;
    int* cursor = offs + NN + 1;
    int* csr_col = cursor + NN;

    hipMemsetAsync(cnt, 0, NN * sizeof(int), stream);
    k_count<<<NE / 256, 256, 0, stream>>>(erow, cnt);
    k_scan<<<1, 1024, 0, stream>>>(cnt, offs, cursor);
    k_scatter<<<NE / 256, 256, 0, stream>>>(erow, ecol, cursor, csr_col);
    k_ln_qkv<<<NN / 64, 256, 0, stream>>>(x, ln1g, ln1b, wq, bq, wk, bk, wv, bv, qb, kb, vb);
    k_attn<<<NN / 4, 256, 0, stream>>>(qb, kb, vb, offs, csr_col, aggb);
    k_wo_res<<<NN / 64, 256, 0, stream>>>(aggb, wo, bo, x, out);
    k_ln2_mlp1<<<dim3(NN / 64, 2), 256, 0, stream>>>(out, ln2g, ln2b, w1, b1, tbuf);
    k_mlp2_res<<<NN / 64, 256, 0, stream>>>(tbuf, w2, b2, out);
}

// Round 4
// 339.273 us; speedup vs baseline: 1.7532x; 1.7532x over previous
//
#include <hip/hip_runtime.h>
#include <math.h>

#define NN 65536
#define HH 128
#define DHH 16
#define NE 1048576
#define HID 256
#define LNEPS 1e-5f

typedef __attribute__((ext_vector_type(8))) short bf16x8;
typedef __attribute__((ext_vector_type(8))) unsigned short u16x8;
typedef __attribute__((ext_vector_type(4))) float f32x4;

static __device__ __forceinline__ unsigned short f2bf(float f) {
    union { float f; unsigned u; } c; c.f = f;
    unsigned r = c.u + 0x7fffu + ((c.u >> 16) & 1u);
    return (unsigned short)(r >> 16);
}
static __device__ __forceinline__ float bf2f(unsigned short u) {
    union { unsigned u; float f; } c; c.u = ((unsigned)u) << 16;
    return c.f;
}
static __device__ __forceinline__ float gelu_tanh(float x) {
    const float c = 0.7978845608028654f;
    return 0.5f * x * (1.f + tanhf(c * (x + 0.044715f * x * x * x)));
}

// ---------------- CSR build ----------------
__global__ __launch_bounds__(256) void k_count(const int* __restrict__ er, int* __restrict__ cnt) {
    int e = blockIdx.x * 256 + threadIdx.x;
    atomicAdd(&cnt[er[e]], 1);
}

__global__ __launch_bounds__(1024) void k_scan(const int* __restrict__ cnt,
                                               int* __restrict__ offs, int* __restrict__ cursor) {
    __shared__ int part[1024];
    const int t = threadIdx.x;
    const int base = t * 64;
    int sum = 0;
    for (int i = 0; i < 64; i++) sum += cnt[base + i];
    part[t] = sum;
    __syncthreads();
    for (int d = 1; d < 1024; d <<= 1) {
        int vv = (t >= d) ? part[t - d] : 0;
        __syncthreads();
        part[t] += vv;
        __syncthreads();
    }
    int run = part[t] - sum;
    for (int i = 0; i < 64; i++) {
        offs[base + i] = run;
        cursor[base + i] = run;
        run += cnt[base + i];
    }
    if (t == 1023) offs[NN] = run;
}

__global__ __launch_bounds__(256) void k_scatter(const int* __restrict__ er, const int* __restrict__ ec,
                                                 int* __restrict__ cursor, int* __restrict__ csr_col) {
    int e = blockIdx.x * 256 + threadIdx.x;
    int r = er[e];
    int p = atomicAdd(&cursor[r], 1);
    csr_col[p] = ec[e];
}

// ---------------- weight pack: fp32 W[K][N] -> bf16 Wp[(k>>3)*N + n][8] ----------------
__global__ __launch_bounds__(256) void k_pack(
    const float* __restrict__ wq, const float* __restrict__ wk, const float* __restrict__ wv,
    const float* __restrict__ wo, const float* __restrict__ w1, const float* __restrict__ w2,
    unsigned short* __restrict__ p) {
    const int b = blockIdx.x, t = threadIdx.x;
    const float* src; unsigned short* dst; int N, idx;
    if (b < 64)       { src = wq; dst = p;          N = 128; idx = b * 256 + t; }
    else if (b < 128) { src = wk; dst = p + 16384;  N = 128; idx = (b - 64) * 256 + t; }
    else if (b < 192) { src = wv; dst = p + 32768;  N = 128; idx = (b - 128) * 256 + t; }
    else if (b < 256) { src = wo; dst = p + 49152;  N = 128; idx = (b - 192) * 256 + t; }
    else if (b < 384) { src = w1; dst = p + 65536;  N = 256; idx = (b - 256) * 256 + t; }
    else              { src = w2; dst = p + 98304;  N = 128; idx = (b - 384) * 256 + t; }
    const int k = idx / N, n = idx % N;
    dst[(((k >> 3) * N + n) << 3) + (k & 7)] = f2bf(src[idx]);
}

// ---------------- K1: LN1 + QKV (MFMA bf16) ----------------
__global__ __launch_bounds__(256) void k_ln_qkv(
    const float* __restrict__ x, const float* __restrict__ g, const float* __restrict__ bl,
    const unsigned short* __restrict__ wqp, const float* __restrict__ bq,
    const unsigned short* __restrict__ wkp, const float* __restrict__ bk,
    const unsigned short* __restrict__ wvp, const float* __restrict__ bv,
    unsigned short* __restrict__ qo, unsigned short* __restrict__ ko, unsigned short* __restrict__ vo) {
    __shared__ unsigned short aT[64 * 128];
    const int t = threadIdx.x;
    const int rb = blockIdx.x * 64;
    {
        const int r = t >> 2, qd = t & 3;
        const float4* xr = reinterpret_cast<const float4*>(x + (size_t)(rb + r) * HH) + qd * 8;
        float xa[32]; float s = 0.f, ss = 0.f;
#pragma unroll
        for (int i = 0; i < 8; i++) {
            float4 v4 = xr[i];
            xa[i * 4 + 0] = v4.x; xa[i * 4 + 1] = v4.y; xa[i * 4 + 2] = v4.z; xa[i * 4 + 3] = v4.w;
            s += v4.x + v4.y + v4.z + v4.w;
            ss += v4.x * v4.x + v4.y * v4.y + v4.z * v4.z + v4.w * v4.w;
        }
        s += __shfl_xor(s, 1); s += __shfl_xor(s, 2);
        ss += __shfl_xor(ss, 1); ss += __shfl_xor(ss, 2);
        const float mu = s * (1.f / HH);
        const float rs = rsqrtf(ss * (1.f / HH) - mu * mu + LNEPS);
#pragma unroll
        for (int c = 0; c < 4; c++) {
            u16x8 w8;
#pragma unroll
            for (int j2 = 0; j2 < 8; j2++) {
                const int d = qd * 32 + c * 8 + j2;
                w8[j2] = f2bf((xa[c * 8 + j2] - mu) * rs * g[d] + bl[d]);
            }
            const int uoff = (r * 128 + qd * 32 + c * 8) ^ ((r & 7) << 3);
            *reinterpret_cast<u16x8*>(&aT[uoff]) = w8;
        }
    }
    __syncthreads();
    const int w = t >> 6, l = t & 63;
    const int m0 = w * 16, lr = l & 15, lg = l >> 4;
    const int row = m0 + lr;
    bf16x8 a[4];
#pragma unroll
    for (int kc = 0; kc < 4; kc++)
        a[kc] = *reinterpret_cast<const bf16x8*>(&aT[(row * 128 + kc * 32 + lg * 8) ^ ((row & 7) << 3)]);

#pragma unroll 1
    for (int m = 0; m < 3; m++) {
        const unsigned short* Wp = (m == 0) ? wqp : (m == 1) ? wkp : wvp;
        const float* Bb = (m == 0) ? bq : (m == 1) ? bk : bv;
        unsigned short* O = (m == 0) ? qo : (m == 1) ? ko : vo;
        f32x4 acc[8];
#pragma unroll
        for (int g8 = 0; g8 < 8; g8++) acc[g8] = (f32x4){0.f, 0.f, 0.f, 0.f};
#pragma unroll
        for (int g8 = 0; g8 < 8; g8++)
#pragma unroll
            for (int kc = 0; kc < 4; kc++)
                acc[g8] = __builtin_amdgcn_mfma_f32_16x16x32_bf16(
                    a[kc],
                    *reinterpret_cast<const bf16x8*>(Wp + ((((kc << 2) + lg) * 128 + g8 * 16 + lr) << 3)),
                    acc[g8], 0, 0, 0);
#pragma unroll
        for (int g8 = 0; g8 < 8; g8++) {
            const float bias = Bb[g8 * 16 + lr];
#pragma unroll
            for (int j = 0; j < 4; j++)
                O[(size_t)(rb + m0 + 4 * lg + j) * HH + g8 * 16 + lr] = f2bf(acc[g8][j] + bias);
        }
    }
}

// ---------------- K3: fused SDDMM + softmax + SpMM (bf16 gather) ----------------
__global__ __launch_bounds__(256) void k_attn(
    const unsigned short* __restrict__ q, const unsigned short* __restrict__ k,
    const unsigned short* __restrict__ v, const int* __restrict__ offs,
    const int* __restrict__ csr_col, unsigned short* __restrict__ agg) {
    const int wave = threadIdx.x >> 6;
    const int lane = threadIdx.x & 63;
    const int row = blockIdx.x * 4 + wave;
    const int h = lane & 7, es = lane >> 3;
    const int c0 = offs[row], c1 = offs[row + 1];
    const int cnt = c1 - c0;

    float qf[16];
    {
        const u16x8* qp = reinterpret_cast<const u16x8*>(q + (size_t)row * HH + h * DHH);
        u16x8 q0 = qp[0], q1 = qp[1];
#pragma unroll
        for (int j = 0; j < 8; j++) { qf[j] = bf2f(q0[j]); qf[8 + j] = bf2f(q1[j]); }
    }
    float m = -INFINITY, den = 0.f;
    float acc[16] = {};

    for (int base = 0; base < cnt; base += 8) {
        const int ei = base + es;
        const bool act = ei < cnt;
        int col = 0;
        if (act) col = csr_col[c0 + ei];
        float sc = -INFINITY;
        float vf[16];
        if (act) {
            const u16x8* kp = reinterpret_cast<const u16x8*>(k + (size_t)col * HH + h * DHH);
            const u16x8* vp = reinterpret_cast<const u16x8*>(v + (size_t)col * HH + h * DHH);
            u16x8 k0 = kp[0], k1 = kp[1];
            u16x8 v0 = vp[0], v1 = vp[1];
            float dot = 0.f;
#pragma unroll
            for (int j = 0; j < 8; j++) {
                dot += qf[j] * bf2f(k0[j]) + qf[8 + j] * bf2f(k1[j]);
                vf[j] = bf2f(v0[j]); vf[8 + j] = bf2f(v1[j]);
            }
            sc = dot * 0.25f;  // 1/sqrt(16)
        }
        float cm = sc;
        cm = fmaxf(cm, __shfl_xor(cm, 8));
        cm = fmaxf(cm, __shfl_xor(cm, 16));
        cm = fmaxf(cm, __shfl_xor(cm, 32));
        const float nm = fmaxf(m, cm);
        const float scale = expf(m - nm);
        const float p = act ? expf(sc - nm) : 0.f;
        den = den * scale + p;
#pragma unroll
        for (int i = 0; i < 16; i++) acc[i] *= scale;
        if (act) {
#pragma unroll
            for (int i = 0; i < 16; i++) acc[i] += p * vf[i];
        }
        m = nm;
    }
#pragma unroll
    for (int d = 8; d < 64; d <<= 1) {
        den += __shfl_xor(den, d);
#pragma unroll
        for (int i = 0; i < 16; i++) acc[i] += __shfl_xor(acc[i], d);
    }
    const float inv = 1.f / (den + 1e-9f);
    if (es == 0) {
        unsigned short* ar = agg + (size_t)row * HH + h * DHH;
        u16x8 o0, o1;
#pragma unroll
        for (int j = 0; j < 8; j++) { o0[j] = f2bf(acc[j] * inv); o1[j] = f2bf(acc[8 + j] * inv); }
        reinterpret_cast<u16x8*>(ar)[0] = o0;
        reinterpret_cast<u16x8*>(ar)[1] = o1;
    }
}

// ---------------- K4: fused wo+residual+LN2+MLP1+gelu+MLP2+residual ----------------
__global__ __launch_bounds__(256) void k_tail(
    const unsigned short* __restrict__ aggb, const unsigned short* __restrict__ wop,
    const float* __restrict__ bo, const float* __restrict__ x,
    const float* __restrict__ g2, const float* __restrict__ bl2,
    const unsigned short* __restrict__ w1p, const float* __restrict__ b1,
    const unsigned short* __restrict__ w2p, const float* __restrict__ b2,
    float* __restrict__ out) {
    __shared__ unsigned short aT[64 * 128];   // agg tile, then hn tile (reused)
    __shared__ unsigned short tT[64 * 256];   // gelu(mlp1) tile
    const int t = threadIdx.x;
    const int rb = blockIdx.x * 64;
    {
        const int r = t >> 2, qd = t & 3;
        const u16x8* src = reinterpret_cast<const u16x8*>(aggb + (size_t)(rb + r) * HH) + qd * 4;
#pragma unroll
        for (int c = 0; c < 4; c++) {
            const int uoff = (r * 128 + qd * 32 + c * 8) ^ ((r & 7) << 3);
            *reinterpret_cast<u16x8*>(&aT[uoff]) = src[c];
        }
    }
    __syncthreads();
    const int w = t >> 6, l = t & 63;
    const int m0 = w * 16, lr = l & 15, lg = l >> 4;
    const int row = m0 + lr;

    // ---- agg @ wo ----
    bf16x8 a[4];
#pragma unroll
    for (int kc = 0; kc < 4; kc++)
        a[kc] = *reinterpret_cast<const bf16x8*>(&aT[(row * 128 + kc * 32 + lg * 8) ^ ((row & 7) << 3)]);
    f32x4 acc[8];
#pragma unroll
    for (int g8 = 0; g8 < 8; g8++) acc[g8] = (f32x4){0.f, 0.f, 0.f, 0.f};
#pragma unroll
    for (int g8 = 0; g8 < 8; g8++)
#pragma unroll
        for (int kc = 0; kc < 4; kc++)
            acc[g8] = __builtin_amdgcn_mfma_f32_16x16x32_bf16(
                a[kc],
                *reinterpret_cast<const bf16x8*>(wop + ((((kc << 2) + lg) * 128 + g8 * 16 + lr) << 3)),
                acc[g8], 0, 0, 0);
    // h = acc + bo + x  (kept in registers, fp32)
    float hv[8][4];
#pragma unroll
    for (int g8 = 0; g8 < 8; g8++) {
        const float bias = bo[g8 * 16 + lr];
#pragma unroll
        for (int j = 0; j < 4; j++)
            hv[g8][j] = acc[g8][j] + bias + x[(size_t)(rb + m0 + 4 * lg + j) * HH + g8 * 16 + lr];
    }
    // ---- LN2: row m0+4*lg+j lives in lane-group lg; reduce across its 16 lanes ----
    float mu[4], rs[4];
#pragma unroll
    for (int j = 0; j < 4; j++) {
        float s = 0.f, ss = 0.f;
#pragma unroll
        for (int g8 = 0; g8 < 8; g8++) { const float hh = hv[g8][j]; s += hh; ss += hh * hh; }
        s += __shfl_xor(s, 1); s += __shfl_xor(s, 2); s += __shfl_xor(s, 4); s += __shfl_xor(s, 8);
        ss += __shfl_xor(ss, 1); ss += __shfl_xor(ss, 2); ss += __shfl_xor(ss, 4); ss += __shfl_xor(ss, 8);
        mu[j] = s * (1.f / HH);
        rs[j] = rsqrtf(ss * (1.f / HH) - mu[j] * mu[j] + LNEPS);
    }
    __syncthreads();  // all aT reads complete; safe to overwrite with hn
#pragma unroll
    for (int g8 = 0; g8 < 8; g8++) {
        const float gg = g2[g8 * 16 + lr], bb = bl2[g8 * 16 + lr];
#pragma unroll
        for (int j = 0; j < 4; j++) {
            const int i = m0 + 4 * lg + j;   // FIX: wave offset m0 was missing
            aT[(i * 128 + g8 * 16 + lr) ^ ((i & 7) << 3)] = f2bf((hv[g8][j] - mu[j]) * rs[j] * gg + bb);
        }
    }
    __syncthreads();
    // ---- mlp1: hn @ w1 (K=128, N=256) + gelu -> tT ----
    bf16x8 a2[4];
#pragma unroll
    for (int kc = 0; kc < 4; kc++)
        a2[kc] = *reinterpret_cast<const bf16x8*>(&aT[(row * 128 + kc * 32 + lg * 8) ^ ((row & 7) << 3)]);
#pragma unroll 1
    for (int G = 0; G < 16; G++) {
        f32x4 a1 = (f32x4){0.f, 0.f, 0.f, 0.f};
#pragma unroll
        for (int kc = 0; kc < 4; kc++)
            a1 = __builtin_amdgcn_mfma_f32_16x16x32_bf16(
                a2[kc],
                *reinterpret_cast<const bf16x8*>(w1p + ((((kc << 2) + lg) * 256 + G * 16 + lr) << 3)),
                a1, 0, 0, 0);
        const float bias = b1[G * 16 + lr];
#pragma unroll
        for (int j = 0; j < 4; j++) {
            const int i = m0 + 4 * lg + j;   // FIX: wave offset m0 was missing
            tT[(i * 256 + G * 16 + lr) ^ ((i & 7) << 3)] = f2bf(gelu_tanh(a1[j] + bias));
        }
    }
    __syncthreads();
    // ---- mlp2: t @ w2 (K=256, N=128) + h + b2 -> out ----
    bf16x8 a3[8];
#pragma unroll
    for (int kc = 0; kc < 8; kc++)
        a3[kc] = *reinterpret_cast<const bf16x8*>(&tT[(row * 256 + kc * 32 + lg * 8) ^ ((row & 7) << 3)]);
#pragma unroll 1
    for (int g8 = 0; g8 < 8; g8++) {
        f32x4 a2c = (f32x4){0.f, 0.f, 0.f, 0.f};
#pragma unroll
        for (int kc = 0; kc < 8; kc++)
            a2c = __builtin_amdgcn_mfma_f32_16x16x32_bf16(
                a3[kc],
                *reinterpret_cast<const bf16x8*>(w2p + ((((kc << 2) + lg) * 128 + g8 * 16 + lr) << 3)),
                a2c, 0, 0, 0);
        const float bias = b2[g8 * 16 + lr];
#pragma unroll
        for (int j = 0; j < 4; j++)
            out[(size_t)(rb + m0 + 4 * lg + j) * HH + g8 * 16 + lr] = hv[g8][j] + a2c[j] + bias;
    }
}

extern "C" void kernel_launch(void* const* d_in, const int* in_sizes, int n_in,
                              void* d_out, int out_size, void* d_ws, size_t ws_size,
                              hipStream_t stream) {
    const float* x = (const float*)d_in[0];
    const int* erow = (const int*)d_in[1];
    const int* ecol = (const int*)d_in[2];
    const float* ln1g = (const float*)d_in[3];
    const float* ln1b = (const float*)d_in[4];
    const float* wq = (const float*)d_in[5];
    const float* bq = (const float*)d_in[6];
    const float* wk = (const float*)d_in[7];
    const float* bk = (const float*)d_in[8];
    const float* wv = (const float*)d_in[9];
    const float* bv = (const float*)d_in[10];
    const float* wo = (const float*)d_in[11];
    const float* bo = (const float*)d_in[12];
    const float* ln2g = (const float*)d_in[13];
    const float* ln2b = (const float*)d_in[14];
    const float* w1 = (const float*)d_in[15];
    const float* b1 = (const float*)d_in[16];
    const float* w2 = (const float*)d_in[17];
    const float* b2 = (const float*)d_in[18];
    float* out = (float*)d_out;

    unsigned short* qb = (unsigned short*)d_ws;
    unsigned short* kb = qb + (size_t)NN * HH;
    unsigned short* vb = kb + (size_t)NN * HH;
    unsigned short* aggb = vb + (size_t)NN * HH;
    unsigned short* wpack = aggb + (size_t)NN * HH;   // 131072 ushorts
    int* cnt = (int*)(wpack + 131072);
    int* offs = cnt + NN;
    int* cursor = offs + NN + 1;
    int* csr_col = cursor + NN;

    hipMemsetAsync(cnt, 0, NN * sizeof(int), stream);
    k_pack<<<512, 256, 0, stream>>>(wq, wk, wv, wo, w1, w2, wpack);
    k_count<<<NE / 256, 256, 0, stream>>>(erow, cnt);
    k_scan<<<1, 1024, 0, stream>>>(cnt, offs, cursor);
    k_scatter<<<NE / 256, 256, 0, stream>>>(erow, ecol, cursor, csr_col);
    k_ln_qkv<<<NN / 64, 256, 0, stream>>>(x, ln1g, ln1b,
                                          wpack, bq, wpack + 16384, bk, wpack + 32768, bv,
                                          qb, kb, vb);
    k_attn<<<NN / 4, 256, 0, stream>>>(qb, kb, vb, offs, csr_col, aggb);
    k_tail<<<NN / 64, 256, 0, stream>>>(aggb, wpack + 49152, bo, x, ln2g, ln2b,
                                        wpack + 65536, b1, wpack + 98304, b2, out);
}

// Round 5
// 307.545 us; speedup vs baseline: 1.9341x; 1.1032x over previous
//
#include <hip/hip_runtime.h>
#include <math.h>

#define NN 65536
#define HH 128
#define DHH 16
#define NE 1048576
#define HID 256
#define LNEPS 1e-5f

typedef __attribute__((ext_vector_type(8))) short bf16x8;
typedef __attribute__((ext_vector_type(8))) unsigned short u16x8;
typedef __attribute__((ext_vector_type(4))) float f32x4;

static __device__ __forceinline__ unsigned short f2bf(float f) {
    union { float f; unsigned u; } c; c.f = f;
    unsigned r = c.u + 0x7fffu + ((c.u >> 16) & 1u);
    return (unsigned short)(r >> 16);
}
static __device__ __forceinline__ float bf2f(unsigned short u) {
    union { unsigned u; float f; } c; c.u = ((unsigned)u) << 16;
    return c.f;
}
static __device__ __forceinline__ float gelu_tanh(float x) {
    const float c = 0.7978845608028654f;
    return 0.5f * x * (1.f + tanhf(c * (x + 0.044715f * x * x * x)));
}

// ---------------- CSR build ----------------
__global__ __launch_bounds__(256) void k_count(const int* __restrict__ er, int* __restrict__ cnt) {
    int e = blockIdx.x * 256 + threadIdx.x;
    atomicAdd(&cnt[er[e]], 1);
}

// parallel scan, stage 1: per-block (256 elems) sums
__global__ __launch_bounds__(256) void k_scan1(const int* __restrict__ cnt, int* __restrict__ bsum) {
    const int t = threadIdx.x;
    int v = cnt[blockIdx.x * 256 + t];
#pragma unroll
    for (int d = 1; d < 64; d <<= 1) v += __shfl_xor(v, d);
    __shared__ int ws[4];
    if ((t & 63) == 0) ws[t >> 6] = v;
    __syncthreads();
    if (t == 0) bsum[blockIdx.x] = ws[0] + ws[1] + ws[2] + ws[3];
}

// parallel scan, stage 2: block base from bsum prefix + intra-block scan
__global__ __launch_bounds__(256) void k_scan2(const int* __restrict__ cnt, const int* __restrict__ bsum,
                                               int* __restrict__ offs, int* __restrict__ cursor) {
    const int b = blockIdx.x, t = threadIdx.x;
    __shared__ int pref[256];
    __shared__ int sc2[256];
    __shared__ int base_s;
    pref[t] = bsum[t];
    __syncthreads();
    for (int d = 1; d < 256; d <<= 1) {
        int vv = (t >= d) ? pref[t - d] : 0;
        __syncthreads();
        pref[t] += vv;
        __syncthreads();
    }
    if (t == 0) base_s = (b == 0) ? 0 : pref[b - 1];
    __syncthreads();
    const int v = cnt[b * 256 + t];
    sc2[t] = v;
    __syncthreads();
    for (int d = 1; d < 256; d <<= 1) {
        int vv = (t >= d) ? sc2[t - d] : 0;
        __syncthreads();
        sc2[t] += vv;
        __syncthreads();
    }
    const int excl = base_s + sc2[t] - v;
    offs[b * 256 + t] = excl;
    cursor[b * 256 + t] = excl;
    if (b == 255 && t == 255) offs[NN] = base_s + sc2[255];
}

__global__ __launch_bounds__(256) void k_scatter(const int* __restrict__ er, const int* __restrict__ ec,
                                                 int* __restrict__ cursor, int* __restrict__ csr_col) {
    int e = blockIdx.x * 256 + threadIdx.x;
    int r = er[e];
    int p = atomicAdd(&cursor[r], 1);
    csr_col[p] = ec[e];
}

// ---------------- weight pack: fp32 W[K][N] -> bf16 Wp[(k>>3)*N + n][8] ----------------
__global__ __launch_bounds__(256) void k_pack(
    const float* __restrict__ wq, const float* __restrict__ wk, const float* __restrict__ wv,
    const float* __restrict__ wo, const float* __restrict__ w1, const float* __restrict__ w2,
    unsigned short* __restrict__ p) {
    const int b = blockIdx.x, t = threadIdx.x;
    const float* src; unsigned short* dst; int N, idx;
    if (b < 64)       { src = wq; dst = p;          N = 128; idx = b * 256 + t; }
    else if (b < 128) { src = wk; dst = p + 16384;  N = 128; idx = (b - 64) * 256 + t; }
    else if (b < 192) { src = wv; dst = p + 32768;  N = 128; idx = (b - 128) * 256 + t; }
    else if (b < 256) { src = wo; dst = p + 49152;  N = 128; idx = (b - 192) * 256 + t; }
    else if (b < 384) { src = w1; dst = p + 65536;  N = 256; idx = (b - 256) * 256 + t; }
    else              { src = w2; dst = p + 98304;  N = 128; idx = (b - 384) * 256 + t; }
    const int k = idx / N, n = idx % N;
    dst[(((k >> 3) * N + n) << 3) + (k & 7)] = f2bf(src[idx]);
}

// ---------------- K1: LN1 + QKV (MFMA bf16, 128 rows/block, 32 rows/wave) ----------------
__global__ __launch_bounds__(256) void k_ln_qkv(
    const float* __restrict__ x, const float* __restrict__ g, const float* __restrict__ bl,
    const unsigned short* __restrict__ wqp, const float* __restrict__ bq,
    const unsigned short* __restrict__ wkp, const float* __restrict__ bk,
    const unsigned short* __restrict__ wvp, const float* __restrict__ bv,
    unsigned short* __restrict__ qo, unsigned short* __restrict__ ko, unsigned short* __restrict__ vo) {
    __shared__ unsigned short aT[128 * 128];  // 32 KB
    const int t = threadIdx.x;
    const int rb = blockIdx.x * 128;
    {
        const int r = t >> 2, qd = t & 3;
#pragma unroll 1
        for (int rr = 0; rr < 2; rr++) {
            const int row = r + rr * 64;
            const float4* xr = reinterpret_cast<const float4*>(x + (size_t)(rb + row) * HH) + qd * 8;
            float xa[32]; float s = 0.f, ss = 0.f;
#pragma unroll
            for (int i = 0; i < 8; i++) {
                float4 v4 = xr[i];
                xa[i * 4 + 0] = v4.x; xa[i * 4 + 1] = v4.y; xa[i * 4 + 2] = v4.z; xa[i * 4 + 3] = v4.w;
                s += v4.x + v4.y + v4.z + v4.w;
                ss += v4.x * v4.x + v4.y * v4.y + v4.z * v4.z + v4.w * v4.w;
            }
            s += __shfl_xor(s, 1); s += __shfl_xor(s, 2);
            ss += __shfl_xor(ss, 1); ss += __shfl_xor(ss, 2);
            const float mu = s * (1.f / HH);
            const float rs = rsqrtf(ss * (1.f / HH) - mu * mu + LNEPS);
#pragma unroll
            for (int c = 0; c < 4; c++) {
                u16x8 w8;
#pragma unroll
                for (int j2 = 0; j2 < 8; j2++) {
                    const int d = qd * 32 + c * 8 + j2;
                    w8[j2] = f2bf((xa[c * 8 + j2] - mu) * rs * g[d] + bl[d]);
                }
                const int uoff = (row * 128 + qd * 32 + c * 8) ^ ((row & 7) << 3);
                *reinterpret_cast<u16x8*>(&aT[uoff]) = w8;
            }
        }
    }
    __syncthreads();
    const int w = t >> 6, l = t & 63;
    const int lr = l & 15, lg = l >> 4;
    const int row0 = w * 32 + lr;
    const int row1 = w * 32 + 16 + lr;
    bf16x8 a0[4], a1[4];
#pragma unroll
    for (int kc = 0; kc < 4; kc++) {
        a0[kc] = *reinterpret_cast<const bf16x8*>(&aT[(row0 * 128 + kc * 32 + lg * 8) ^ ((row0 & 7) << 3)]);
        a1[kc] = *reinterpret_cast<const bf16x8*>(&aT[(row1 * 128 + kc * 32 + lg * 8) ^ ((row1 & 7) << 3)]);
    }

#pragma unroll 1
    for (int m = 0; m < 3; m++) {
        const unsigned short* Wp = (m == 0) ? wqp : (m == 1) ? wkp : wvp;
        const float* Bb = (m == 0) ? bq : (m == 1) ? bk : bv;
        unsigned short* O = (m == 0) ? qo : (m == 1) ? ko : vo;
        f32x4 ac0[8], ac1[8];
#pragma unroll
        for (int g8 = 0; g8 < 8; g8++) { ac0[g8] = (f32x4){0.f,0.f,0.f,0.f}; ac1[g8] = (f32x4){0.f,0.f,0.f,0.f}; }
#pragma unroll
        for (int g8 = 0; g8 < 8; g8++)
#pragma unroll
            for (int kc = 0; kc < 4; kc++) {
                const bf16x8 bfr = *reinterpret_cast<const bf16x8*>(Wp + ((((kc << 2) + lg) * 128 + g8 * 16 + lr) << 3));
                ac0[g8] = __builtin_amdgcn_mfma_f32_16x16x32_bf16(a0[kc], bfr, ac0[g8], 0, 0, 0);
                ac1[g8] = __builtin_amdgcn_mfma_f32_16x16x32_bf16(a1[kc], bfr, ac1[g8], 0, 0, 0);
            }
#pragma unroll
        for (int g8 = 0; g8 < 8; g8++) {
            const float bias = Bb[g8 * 16 + lr];
#pragma unroll
            for (int j = 0; j < 4; j++) {
                O[(size_t)(rb + w * 32 + 4 * lg + j) * HH + g8 * 16 + lr] = f2bf(ac0[g8][j] + bias);
                O[(size_t)(rb + w * 32 + 16 + 4 * lg + j) * HH + g8 * 16 + lr] = f2bf(ac1[g8][j] + bias);
            }
        }
    }
}

// ---------------- K3: fused SDDMM + softmax + SpMM (bf16 gather, defer-max) ----------------
__global__ __launch_bounds__(256) void k_attn(
    const unsigned short* __restrict__ q, const unsigned short* __restrict__ k,
    const unsigned short* __restrict__ v, const int* __restrict__ offs,
    const int* __restrict__ csr_col, unsigned short* __restrict__ agg) {
    const int wave = threadIdx.x >> 6;
    const int lane = threadIdx.x & 63;
    const int row = blockIdx.x * 4 + wave;
    const int h = lane & 7, es = lane >> 3;
    const int c0 = offs[row], c1 = offs[row + 1];
    const int cnt = c1 - c0;

    float qf[16];
    {
        const u16x8* qp = reinterpret_cast<const u16x8*>(q + (size_t)row * HH + h * DHH);
        u16x8 q0 = qp[0], q1 = qp[1];
#pragma unroll
        for (int j = 0; j < 8; j++) { qf[j] = bf2f(q0[j]); qf[8 + j] = bf2f(q1[j]); }
    }
    float m = 0.f, den = 0.f;
    float acc[16] = {};

    for (int base = 0; base < cnt; base += 8) {
        const int ei = base + es;
        const bool act = ei < cnt;
        int col = 0;
        if (act) col = csr_col[c0 + ei];
        float sc = -INFINITY;
        float vf[16];
        if (act) {
            const u16x8* kp = reinterpret_cast<const u16x8*>(k + (size_t)col * HH + h * DHH);
            const u16x8* vp = reinterpret_cast<const u16x8*>(v + (size_t)col * HH + h * DHH);
            u16x8 k0 = kp[0], k1 = kp[1];
            u16x8 v0 = vp[0], v1 = vp[1];
            float dot = 0.f;
#pragma unroll
            for (int j = 0; j < 8; j++) {
                dot += qf[j] * bf2f(k0[j]) + qf[8 + j] * bf2f(k1[j]);
                vf[j] = bf2f(v0[j]); vf[8 + j] = bf2f(v1[j]);
            }
            sc = dot * 0.25f;  // 1/sqrt(16)
        }
        float cm = sc;
        cm = fmaxf(cm, __shfl_xor(cm, 8));
        cm = fmaxf(cm, __shfl_xor(cm, 16));
        cm = fmaxf(cm, __shfl_xor(cm, 32));
        if (base == 0) {
            m = cm;                                      // first chunk: acc/den are 0, no rescale needed
        } else if (!__all(cm <= m + 8.f)) {              // defer-max: rescale ~never (score sd ~0.3)
            const float nm = fmaxf(m, cm);
            const float s8 = expf(m - nm);
            den *= s8;
#pragma unroll
            for (int i = 0; i < 16; i++) acc[i] *= s8;
            m = nm;
        }
        const float p = act ? expf(sc - m) : 0.f;        // bounded by e^8
        den += p;
        if (act) {
#pragma unroll
            for (int i = 0; i < 16; i++) acc[i] += p * vf[i];
        }
    }
#pragma unroll
    for (int d = 8; d < 64; d <<= 1) {
        den += __shfl_xor(den, d);
#pragma unroll
        for (int i = 0; i < 16; i++) acc[i] += __shfl_xor(acc[i], d);
    }
    const float inv = 1.f / (den + 1e-9f);
    if (es == 0) {
        unsigned short* ar = agg + (size_t)row * HH + h * DHH;
        u16x8 o0, o1;
#pragma unroll
        for (int j = 0; j < 8; j++) { o0[j] = f2bf(acc[j] * inv); o1[j] = f2bf(acc[8 + j] * inv); }
        reinterpret_cast<u16x8*>(ar)[0] = o0;
        reinterpret_cast<u16x8*>(ar)[1] = o1;
    }
}

// ---------------- K4: fused wo+residual+LN2+MLP1+gelu+MLP2+residual ----------------
__global__ __launch_bounds__(256) void k_tail(
    const unsigned short* __restrict__ aggb, const unsigned short* __restrict__ wop,
    const float* __restrict__ bo, const float* __restrict__ x,
    const float* __restrict__ g2, const float* __restrict__ bl2,
    const unsigned short* __restrict__ w1p, const float* __restrict__ b1,
    const unsigned short* __restrict__ w2p, const float* __restrict__ b2,
    float* __restrict__ out) {
    __shared__ unsigned short aT[64 * 128];   // agg tile, then hn tile (reused)
    __shared__ unsigned short tT[64 * 256];   // gelu(mlp1) tile
    const int t = threadIdx.x;
    const int rb = blockIdx.x * 64;
    {
        const int r = t >> 2, qd = t & 3;
        const u16x8* src = reinterpret_cast<const u16x8*>(aggb + (size_t)(rb + r) * HH) + qd * 4;
#pragma unroll
        for (int c = 0; c < 4; c++) {
            const int uoff = (r * 128 + qd * 32 + c * 8) ^ ((r & 7) << 3);
            *reinterpret_cast<u16x8*>(&aT[uoff]) = src[c];
        }
    }
    __syncthreads();
    const int w = t >> 6, l = t & 63;
    const int m0 = w * 16, lr = l & 15, lg = l >> 4;
    const int row = m0 + lr;

    // ---- agg @ wo ----
    bf16x8 a[4];
#pragma unroll
    for (int kc = 0; kc < 4; kc++)
        a[kc] = *reinterpret_cast<const bf16x8*>(&aT[(row * 128 + kc * 32 + lg * 8) ^ ((row & 7) << 3)]);
    f32x4 acc[8];
#pragma unroll
    for (int g8 = 0; g8 < 8; g8++) acc[g8] = (f32x4){0.f, 0.f, 0.f, 0.f};
#pragma unroll
    for (int g8 = 0; g8 < 8; g8++)
#pragma unroll
        for (int kc = 0; kc < 4; kc++)
            acc[g8] = __builtin_amdgcn_mfma_f32_16x16x32_bf16(
                a[kc],
                *reinterpret_cast<const bf16x8*>(wop + ((((kc << 2) + lg) * 128 + g8 * 16 + lr) << 3)),
                acc[g8], 0, 0, 0);
    // h = acc + bo + x  (kept in registers, fp32)
    float hv[8][4];
#pragma unroll
    for (int g8 = 0; g8 < 8; g8++) {
        const float bias = bo[g8 * 16 + lr];
#pragma unroll
        for (int j = 0; j < 4; j++)
            hv[g8][j] = acc[g8][j] + bias + x[(size_t)(rb + m0 + 4 * lg + j) * HH + g8 * 16 + lr];
    }
    // ---- LN2 ----
    float mu[4], rs[4];
#pragma unroll
    for (int j = 0; j < 4; j++) {
        float s = 0.f, ss = 0.f;
#pragma unroll
        for (int g8 = 0; g8 < 8; g8++) { const float hh = hv[g8][j]; s += hh; ss += hh * hh; }
        s += __shfl_xor(s, 1); s += __shfl_xor(s, 2); s += __shfl_xor(s, 4); s += __shfl_xor(s, 8);
        ss += __shfl_xor(ss, 1); ss += __shfl_xor(ss, 2); ss += __shfl_xor(ss, 4); ss += __shfl_xor(ss, 8);
        mu[j] = s * (1.f / HH);
        rs[j] = rsqrtf(ss * (1.f / HH) - mu[j] * mu[j] + LNEPS);
    }
    __syncthreads();
#pragma unroll
    for (int g8 = 0; g8 < 8; g8++) {
        const float gg = g2[g8 * 16 + lr], bb = bl2[g8 * 16 + lr];
#pragma unroll
        for (int j = 0; j < 4; j++) {
            const int i = m0 + 4 * lg + j;
            aT[(i * 128 + g8 * 16 + lr) ^ ((i & 7) << 3)] = f2bf((hv[g8][j] - mu[j]) * rs[j] * gg + bb);
        }
    }
    __syncthreads();
    // ---- mlp1: hn @ w1 (K=128, N=256) + gelu -> tT ----
    bf16x8 a2[4];
#pragma unroll
    for (int kc = 0; kc < 4; kc++)
        a2[kc] = *reinterpret_cast<const bf16x8*>(&aT[(row * 128 + kc * 32 + lg * 8) ^ ((row & 7) << 3)]);
#pragma unroll 1
    for (int G = 0; G < 16; G++) {
        f32x4 a1 = (f32x4){0.f, 0.f, 0.f, 0.f};
#pragma unroll
        for (int kc = 0; kc < 4; kc++)
            a1 = __builtin_amdgcn_mfma_f32_16x16x32_bf16(
                a2[kc],
                *reinterpret_cast<const bf16x8*>(w1p + ((((kc << 2) + lg) * 256 + G * 16 + lr) << 3)),
                a1, 0, 0, 0);
        const float bias = b1[G * 16 + lr];
#pragma unroll
        for (int j = 0; j < 4; j++) {
            const int i = m0 + 4 * lg + j;
            tT[(i * 256 + G * 16 + lr) ^ ((i & 7) << 3)] = f2bf(gelu_tanh(a1[j] + bias));
        }
    }
    __syncthreads();
    // ---- mlp2: t @ w2 (K=256, N=128) + h + b2 -> out ----
    bf16x8 a3[8];
#pragma unroll
    for (int kc = 0; kc < 8; kc++)
        a3[kc] = *reinterpret_cast<const bf16x8*>(&tT[(row * 256 + kc * 32 + lg * 8) ^ ((row & 7) << 3)]);
#pragma unroll 1
    for (int g8 = 0; g8 < 8; g8++) {
        f32x4 a2c = (f32x4){0.f, 0.f, 0.f, 0.f};
#pragma unroll
        for (int kc = 0; kc < 8; kc++)
            a2c = __builtin_amdgcn_mfma_f32_16x16x32_bf16(
                a3[kc],
                *reinterpret_cast<const bf16x8*>(w2p + ((((kc << 2) + lg) * 128 + g8 * 16 + lr) << 3)),
                a2c, 0, 0, 0);
        const float bias = b2[g8 * 16 + lr];
#pragma unroll
        for (int j = 0; j < 4; j++)
            out[(size_t)(rb + m0 + 4 * lg + j) * HH + g8 * 16 + lr] = hv[g8][j] + a2c[j] + bias;
    }
}

extern "C" void kernel_launch(void* const* d_in, const int* in_sizes, int n_in,
                              void* d_out, int out_size, void* d_ws, size_t ws_size,
                              hipStream_t stream) {
    const float* x = (const float*)d_in[0];
    const int* erow = (const int*)d_in[1];
    const int* ecol = (const int*)d_in[2];
    const float* ln1g = (const float*)d_in[3];
    const float* ln1b = (const float*)d_in[4];
    const float* wq = (const float*)d_in[5];
    const float* bq = (const float*)d_in[6];
    const float* wk = (const float*)d_in[7];
    const float* bk = (const float*)d_in[8];
    const float* wv = (const float*)d_in[9];
    const float* bv = (const float*)d_in[10];
    const float* wo = (const float*)d_in[11];
    const float* bo = (const float*)d_in[12];
    const float* ln2g = (const float*)d_in[13];
    const float* ln2b = (const float*)d_in[14];
    const float* w1 = (const float*)d_in[15];
    const float* b1 = (const float*)d_in[16];
    const float* w2 = (const float*)d_in[17];
    const float* b2 = (const float*)d_in[18];
    float* out = (float*)d_out;

    unsigned short* qb = (unsigned short*)d_ws;
    unsigned short* kb = qb + (size_t)NN * HH;
    unsigned short* vb = kb + (size_t)NN * HH;
    unsigned short* aggb = vb + (size_t)NN * HH;
    unsigned short* wpack = aggb + (size_t)NN * HH;   // 131072 ushorts
    int* cnt = (int*)(wpack + 131072);
    int* offs = cnt + NN;
    int* cursor = offs + NN + 1;
    int* csr_col = cursor + NN;
    int* bsum = csr_col + NE;

    hipMemsetAsync(cnt, 0, NN * sizeof(int), stream);
    k_pack<<<512, 256, 0, stream>>>(wq, wk, wv, wo, w1, w2, wpack);
    k_count<<<NE / 256, 256, 0, stream>>>(erow, cnt);
    k_scan1<<<NN / 256, 256, 0, stream>>>(cnt, bsum);
    k_scan2<<<NN / 256, 256, 0, stream>>>(cnt, bsum, offs, cursor);
    k_scatter<<<NE / 256, 256, 0, stream>>>(erow, ecol, cursor, csr_col);
    k_ln_qkv<<<NN / 128, 256, 0, stream>>>(x, ln1g, ln1b,
                                           wpack, bq, wpack + 16384, bk, wpack + 32768, bv,
                                           qb, kb, vb);
    k_attn<<<NN / 4, 256, 0, stream>>>(qb, kb, vb, offs, csr_col, aggb);
    k_tail<<<NN / 64, 256, 0, stream>>>(aggb, wpack + 49152, bo, x, ln2g, ln2b,
                                        wpack + 65536, b1, wpack + 98304, b2, out);
}